// Round 1
// 613.235 us; speedup vs baseline: 1.0562x; 1.0562x over previous
//
#include <hip/hip_runtime.h>
#include <math.h>

#define A_NODES 50000
#define FEAT 128
#define EDGES 500000
#define NRBF 20
#define CUTOFF_F 5.0f
#define PI_OVER_CUTOFF 0.6283185307179586f

typedef unsigned int uint32;
typedef unsigned short ushort16;
typedef short bf16x8 __attribute__((ext_vector_type(8)));
typedef float f32x4 __attribute__((ext_vector_type(4)));
typedef float f32x2 __attribute__((ext_vector_type(2)));

__device__ __forceinline__ ushort16 f2bf(float f) {
    union { float f; uint32 u; } v; v.f = f;
    uint32 r = (v.u + 0x7fffu + ((v.u >> 16) & 1u)) >> 16;   // RNE
    return (ushort16)r;
}
__device__ __forceinline__ uint32 packbf(float a, float b) {
    return (uint32)f2bf(a) | ((uint32)f2bf(b) << 16);
}
__device__ __forceinline__ float bf_lo(uint32 u) { return __uint_as_float(u << 16); }
__device__ __forceinline__ float bf_hi(uint32 u) { return __uint_as_float(u & 0xffff0000u); }

#if __has_builtin(__builtin_amdgcn_fdot2_f32_bf16)
typedef __bf16 bf16x2 __attribute__((ext_vector_type(2)));
__device__ __forceinline__ float dot2(uint32 a, uint32 b, float c) {
    return __builtin_amdgcn_fdot2_f32_bf16(
        __builtin_bit_cast(bf16x2, a), __builtin_bit_cast(bf16x2, b), c, false);
}
#else
__device__ __forceinline__ float dot2(uint32 a, uint32 b, float c) {
    return fmaf(bf_hi(a), bf_hi(b), fmaf(bf_lo(a), bf_lo(b), c));
}
#endif

// ---------------------------------------------------------------------------
// Weight packing: W1/W2 into MFMA B-fragment order (bf16), Wr into k-pair
// packed bf16x2 (gather layout). One kernel, 69376 elements total.
//   B-frag for mfma_f32_16x16x32_bf16: lane l holds col=(l&15)+16*nt,
//   k = kk*32 + (l>>4)*8 + j, j=0..7 contiguous.
// ---------------------------------------------------------------------------
__global__ __launch_bounds__(256) void pack_kernel(
    const float* __restrict__ W1, const float* __restrict__ W2,
    const float* __restrict__ Wr,
    ushort16* __restrict__ w1pk, ushort16* __restrict__ w2pk,
    uint32* __restrict__ wrpk)
{
    const int t = blockIdx.x * 256 + threadIdx.x;
    if (t < 16384) {
        const int jj = t & 7, l = (t >> 3) & 63, kk = (t >> 9) & 3, nt = t >> 11;
        const int col = (l & 15) + 16 * nt;
        const int k   = kk * 32 + (l >> 4) * 8 + jj;
        w1pk[t] = f2bf(W1[k * 128 + col]);
    } else if (t < 16384 + 49152) {
        const int u = t - 16384;
        const int jj = u & 7, l = (u >> 3) & 63, kk = (u >> 9) & 3, nt = u >> 11;
        const int col = (l & 15) + 16 * nt;
        const int k   = kk * 32 + (l >> 4) * 8 + jj;
        w2pk[u] = f2bf(W2[k * 384 + col]);
    } else if (t < 16384 + 49152 + 3840) {
        const int u = t - 16384 - 49152;
        const int m = u / 384, col = u % 384;
        wrpk[u] = packbf(Wr[(2 * m) * 384 + col], Wr[(2 * m + 1) * 384 + col]);
    }
}

// ---------------------------------------------------------------------------
// Kernel 1: node MLP via MFMA. 16 nodes/block, 4 waves.
// Layer1: each wave does 2 n-tiles of 16 cols (4 waves -> 128).
// Layer2: each wave does 6 n-tiles (4 waves -> 384). silu fused between.
// ---------------------------------------------------------------------------
__global__ __launch_bounds__(256) void node_mlp_kernel(
    const float* __restrict__ scalars,
    const ushort16* __restrict__ w1pk, const float* __restrict__ bias1,
    const ushort16* __restrict__ w2pk, const float* __restrict__ bias2,
    ushort16* __restrict__ s_bf)
{
    __shared__ ushort16 sc[16][136];   // +8 bf16 pad: A-frag reads conflict-light
    __shared__ ushort16 hd[16][136];
    const int tx   = threadIdx.x;
    const int lane = tx & 63;
    const int wv   = tx >> 6;                 // 0..3
    const int base = blockIdx.x * 16;

    // stage scalars -> bf16 LDS (each thread: 8 consecutive floats)
    {
        const int row = tx >> 4;              // 0..15
        const int cs  = (tx & 15) * 8;        // 0,8,...,120
        const float* src = scalars + (size_t)(base + row) * FEAT + cs;
        const float4 f0 = *(const float4*)src;
        const float4 f1 = *(const float4*)(src + 4);
        bf16x8 tmp;
        tmp[0] = (short)f2bf(f0.x); tmp[1] = (short)f2bf(f0.y);
        tmp[2] = (short)f2bf(f0.z); tmp[3] = (short)f2bf(f0.w);
        tmp[4] = (short)f2bf(f1.x); tmp[5] = (short)f2bf(f1.y);
        tmp[6] = (short)f2bf(f1.z); tmp[7] = (short)f2bf(f1.w);
        *(bf16x8*)&sc[row][cs] = tmp;
    }
    __syncthreads();

    const int arow = lane & 15;
    const int kgrp = lane >> 4;               // 0..3

    // ---- layer 1 ----
    f32x4 acc0 = {0.f, 0.f, 0.f, 0.f};
    f32x4 acc1 = {0.f, 0.f, 0.f, 0.f};
    #pragma unroll
    for (int kk = 0; kk < 4; ++kk) {
        const bf16x8 a  = *(const bf16x8*)&sc[arow][kk * 32 + kgrp * 8];
        const bf16x8 b0 = *(const bf16x8*)(w1pk + (((size_t)(wv * 2 + 0) * 4 + kk) * 64 + lane) * 8);
        const bf16x8 b1 = *(const bf16x8*)(w1pk + (((size_t)(wv * 2 + 1) * 4 + kk) * 64 + lane) * 8);
        acc0 = __builtin_amdgcn_mfma_f32_16x16x32_bf16(a, b0, acc0, 0, 0, 0);
        acc1 = __builtin_amdgcn_mfma_f32_16x16x32_bf16(a, b1, acc1, 0, 0, 0);
    }
    // epilogue: +b1, silu, -> hd (C/D: col=lane&15, row=kgrp*4+r)
    {
        const int c0 = wv * 32 + (lane & 15);
        const int c1 = c0 + 16;
        const float bb0 = bias1[c0], bb1 = bias1[c1];
        #pragma unroll
        for (int r = 0; r < 4; ++r) {
            const int row = kgrp * 4 + r;
            float x0 = acc0[r] + bb0;
            float x1 = acc1[r] + bb1;
            x0 = x0 / (1.0f + __expf(-x0));
            x1 = x1 / (1.0f + __expf(-x1));
            hd[row][c0] = f2bf(x0);
            hd[row][c1] = f2bf(x1);
        }
    }
    __syncthreads();

    // ---- layer 2 ----
    f32x4 acc[6];
    #pragma unroll
    for (int n = 0; n < 6; ++n) acc[n] = (f32x4){0.f, 0.f, 0.f, 0.f};
    #pragma unroll
    for (int kk = 0; kk < 4; ++kk) {
        const bf16x8 a = *(const bf16x8*)&hd[arow][kk * 32 + kgrp * 8];
        #pragma unroll
        for (int n = 0; n < 6; ++n) {
            const bf16x8 b = *(const bf16x8*)(w2pk + (((size_t)(wv * 6 + n) * 4 + kk) * 64 + lane) * 8);
            acc[n] = __builtin_amdgcn_mfma_f32_16x16x32_bf16(a, b, acc[n], 0, 0, 0);
        }
    }
    #pragma unroll
    for (int n = 0; n < 6; ++n) {
        const int col = (wv * 6 + n) * 16 + (lane & 15);
        const float bb = bias2[col];
        #pragma unroll
        for (int r = 0; r < 4; ++r) {
            const int row = kgrp * 4 + r;
            s_bf[(size_t)(base + row) * 384 + col] = f2bf(acc[n][r] + bb);
        }
    }
}

// ---------------------------------------------------------------------------
// vectors fp32 -> bf16
// ---------------------------------------------------------------------------
__global__ __launch_bounds__(256) void vec_cvt_kernel(
    const float* __restrict__ vin, uint32* __restrict__ vbf)
{
    const int t = blockIdx.x * 256 + threadIdx.x;
    const size_t n2 = (size_t)A_NODES * 384 / 2;
    if (t < (int)n2) {
        const float a = vin[2 * (size_t)t];
        const float b = vin[2 * (size_t)t + 1];
        vbf[t] = packbf(a, b);
    }
}

// ---------------------------------------------------------------------------
// CSR build
// ---------------------------------------------------------------------------
__global__ __launch_bounds__(256) void hist_kernel(
    const int* __restrict__ idx_j, int* __restrict__ hist)
{
    const int e = blockIdx.x * 256 + threadIdx.x;
    if (e < EDGES) atomicAdd(&hist[idx_j[e]], 1);
}

__global__ __launch_bounds__(1024) void scan_kernel(
    const int* __restrict__ hist, int* __restrict__ offsets,
    int* __restrict__ cursor)
{
    __shared__ int part[1024];
    const int t = threadIdx.x;
    const int CH = (A_NODES + 1023) / 1024;

    int sum = 0;
    for (int k = 0; k < CH; ++k) {
        const int idx = t * CH + k;
        if (idx < A_NODES) sum += hist[idx];
    }
    part[t] = sum;
    __syncthreads();
    for (int off = 1; off < 1024; off <<= 1) {
        const int v = (t >= off) ? part[t - off] : 0;
        __syncthreads();
        part[t] += v;
        __syncthreads();
    }
    int run = part[t] - sum;
    for (int k = 0; k < CH; ++k) {
        const int idx = t * CH + k;
        if (idx < A_NODES) {
            offsets[idx] = run;
            cursor[idx]  = run;
            run += hist[idx];
        }
    }
    if (t == 0) offsets[A_NODES] = EDGES;
}

// ---------------------------------------------------------------------------
// Edge prep FUSED with scatter: e-parallel, coalesced reads, writes edata[pos]
// 16 dwords per position p:
//   [0..9]  rbf*invn*fc packed bf16x2 (k pairs)
//   [10..12] unit dir, [13] fc, [14] idx_i bits, [15] pad
// ---------------------------------------------------------------------------
__global__ __launch_bounds__(256) void edge_prep_kernel(
    const float* __restrict__ directions,
    const int* __restrict__ idx_i, const int* __restrict__ idx_j,
    int* __restrict__ cursor,
    float* __restrict__ edata)
{
    const int e = blockIdx.x * 256 + threadIdx.x;
    if (e >= EDGES) return;
    const int j   = idx_j[e];
    const int pos = atomicAdd(&cursor[j], 1);
    const int i   = idx_i[e];
    const float d0 = directions[(size_t)e * 3 + 0];
    const float d1 = directions[(size_t)e * 3 + 1];
    const float d2 = directions[(size_t)e * 3 + 2];
    const float nr   = sqrtf(d0 * d0 + d1 * d1 + d2 * d2);
    const float invn = 1.0f / nr;
    const float x = PI_OVER_CUTOFF * nr;
    float sx, cx;
    sincosf(x, &sx, &cx);
    const float fc = (nr < CUTOFF_F) ? 0.5f * (cx + 1.0f) : 0.0f;
    const float scale = invn * fc;
    const float twoc = 2.0f * cx;

    float out16[16];
    float s_odd = sx;      // sin((2m+1)x)
    float s_prev = 0.0f;   // sin(2m x)
    #pragma unroll
    for (int m = 0; m < 10; ++m) {
        const float s_even = twoc * s_odd - s_prev;       // sin((2m+2)x)
        out16[m] = __uint_as_float(packbf(s_odd * scale, s_even * scale));
        const float s_next = twoc * s_even - s_odd;       // sin((2m+3)x)
        s_prev = s_even;
        s_odd  = s_next;
    }
    out16[10] = d0 * invn;
    out16[11] = d1 * invn;
    out16[12] = d2 * invn;
    out16[13] = fc;
    out16[14] = __int_as_float(i);
    out16[15] = 0.0f;

    float4* dst = (float4*)(edata + (size_t)pos * 16);
    dst[0] = make_float4(out16[0],  out16[1],  out16[2],  out16[3]);
    dst[1] = make_float4(out16[4],  out16[5],  out16[6],  out16[7]);
    dst[2] = make_float4(out16[8],  out16[9],  out16[10], out16[11]);
    dst[3] = make_float4(out16[12], out16[13], out16[14], out16[15]);
}

// ---------------------------------------------------------------------------
// Gather: block = 1 node x 4 parity waves; lane owns cols 2*lane, 2*lane+1.
// Software-pipelined: next edata row prefetched before compute.
// __launch_bounds__(256,4): 128-VGPR budget so wA/wB stay register-resident.
// ---------------------------------------------------------------------------
template <int VBF>
__global__ __launch_bounds__(256, 4) void gather_kernel(
    const ushort16* __restrict__ s_bf,
    const ushort16* __restrict__ v_bf,
    const float* __restrict__ vectors_f32,
    const uint32* __restrict__ wrpk, const float* __restrict__ br,
    const float* __restrict__ edata,
    const int* __restrict__ offsets,
    float* __restrict__ out_v, float* __restrict__ out_s)
{
    const int lane = threadIdx.x & 63;
    const int wv   = __builtin_amdgcn_readfirstlane(threadIdx.x >> 6);  // 0..3
    const int j    = blockIdx.x;
    const int c0   = lane * 2;

    const int beg = offsets[j];
    const int end = offsets[j + 1];

    float accsA = 0.f, accsB = 0.f;
    float avA0 = 0.f, avA1 = 0.f, avA2 = 0.f;
    float avB0 = 0.f, avB1 = 0.f, avB2 = 0.f;

    uint32 wA[30], wB[30];
    float brA0 = 0.f, brB0 = 0.f, brA1 = 0.f, brB1 = 0.f, brA2 = 0.f, brB2 = 0.f;

    int p = beg + wv;
    float4 cA, cB, cC, cD;

    if (p < end) {
        // preload packed Wr columns (fixed per lane) + biases
        #pragma unroll
        for (int s = 0; s < 3; ++s)
            #pragma unroll
            for (int m = 0; m < 10; ++m) {
                wA[s * 10 + m] = wrpk[m * 384 + s * 128 + c0];
                wB[s * 10 + m] = wrpk[m * 384 + s * 128 + c0 + 1];
            }
        brA0 = br[c0];       brB0 = br[c0 + 1];
        brA1 = br[128 + c0]; brB1 = br[129 + c0];
        brA2 = br[256 + c0]; brB2 = br[257 + c0];

        const float4* s0p = (const float4*)(edata + (size_t)p * 16);
        cA = s0p[0]; cB = s0p[1]; cC = s0p[2]; cD = s0p[3];
    }

    while (p < end) {
        const int pn = p + 4;
        const int i  = __float_as_int(cD.z);     // ed[14]

        // issue gathers for current edge (latency hidden under dot2 chain)
        const ushort16* srow = s_bf + (size_t)i * 384;
        const uint32 s0 = *(const uint32*)(srow + c0);
        const uint32 s1 = *(const uint32*)(srow + 128 + c0);
        const uint32 s2 = *(const uint32*)(srow + 256 + c0);

        float vA0, vB0, vA1, vB1, vA2, vB2;
        if (VBF) {
            const ushort16* vrow = v_bf + (size_t)i * 384;
            const uint32 v0 = *(const uint32*)(vrow + c0);
            const uint32 v1 = *(const uint32*)(vrow + 128 + c0);
            const uint32 v2 = *(const uint32*)(vrow + 256 + c0);
            vA0 = bf_lo(v0); vB0 = bf_hi(v0);
            vA1 = bf_lo(v1); vB1 = bf_hi(v1);
            vA2 = bf_lo(v2); vB2 = bf_hi(v2);
        } else {
            const float* vrow = vectors_f32 + (size_t)i * 384;
            vA0 = vrow[c0];       vB0 = vrow[c0 + 1];
            vA1 = vrow[128 + c0]; vB1 = vrow[129 + c0];
            vA2 = vrow[256 + c0]; vB2 = vrow[257 + c0];
        }

        // prefetch next edata row (safe clamp; uniform -> s_load)
        const size_t pf = (size_t)(pn < end ? pn : p) * 16;
        const float4* sn = (const float4*)(edata + pf);
        const float4 nA = sn[0], nB = sn[1], nC = sn[2], nD = sn[3];

        const float u0 = cC.z, u1 = cC.w, u2 = cD.x;
        const float fcv = cD.y;

        uint32 rb[10] = {
            __float_as_uint(cA.x), __float_as_uint(cA.y),
            __float_as_uint(cA.z), __float_as_uint(cA.w),
            __float_as_uint(cB.x), __float_as_uint(cB.y),
            __float_as_uint(cB.z), __float_as_uint(cB.w),
            __float_as_uint(cC.x), __float_as_uint(cC.y) };

        float rA0 = fcv * brA0, rA1 = fcv * brA1, rA2 = fcv * brA2;
        float rB0 = fcv * brB0, rB1 = fcv * brB1, rB2 = fcv * brB2;
        #pragma unroll
        for (int m = 0; m < 10; ++m) {
            const uint32 rm = rb[m];
            rA0 = dot2(rm, wA[m],      rA0);
            rA1 = dot2(rm, wA[10 + m], rA1);
            rA2 = dot2(rm, wA[20 + m], rA2);
            rB0 = dot2(rm, wB[m],      rB0);
            rB1 = dot2(rm, wB[10 + m], rB1);
            rB2 = dot2(rm, wB[20 + m], rB2);
        }

        const float sA0 = bf_lo(s0), sB0 = bf_hi(s0);
        const float sA1 = bf_lo(s1), sB1 = bf_hi(s1);
        const float sA2 = bf_lo(s2), sB2 = bf_hi(s2);

        accsA = fmaf(sA0, rA0, accsA);
        accsB = fmaf(sB0, rB0, accsB);
        const float gA1 = sA1 * rA1, gA2 = sA2 * rA2;
        const float gB1 = sB1 * rB1, gB2 = sB2 * rB2;

        avA0 = fmaf(vA0, gA1, fmaf(gA2, u0, avA0));
        avB0 = fmaf(vB0, gB1, fmaf(gB2, u0, avB0));
        avA1 = fmaf(vA1, gA1, fmaf(gA2, u1, avA1));
        avB1 = fmaf(vB1, gB1, fmaf(gB2, u1, avB1));
        avA2 = fmaf(vA2, gA1, fmaf(gA2, u2, avA2));
        avB2 = fmaf(vB2, gB1, fmaf(gB2, u2, avB2));

        cA = nA; cB = nB; cC = nC; cD = nD;
        p = pn;
    }

    // combine the 4 parity waves via LDS
    __shared__ float red[4][64][9];
    float* slot = red[wv][lane];
    slot[0] = accsA; slot[1] = accsB;
    slot[2] = avA0;  slot[3] = avB0;
    slot[4] = avA1;  slot[5] = avB1;
    slot[6] = avA2;  slot[7] = avB2;
    __syncthreads();

    if (wv == 0) {
        const float* o1 = red[1][lane];
        const float* o2 = red[2][lane];
        const float* o3 = red[3][lane];
        f32x2 t;
        t.x = accsA + o1[0] + o2[0] + o3[0];
        t.y = accsB + o1[1] + o2[1] + o3[1];
        __builtin_nontemporal_store(t, (f32x2*)(out_s + (size_t)j * 128 + c0));
        float* ov = out_v + (size_t)j * 384;
        t.x = avA0 + o1[2] + o2[2] + o3[2];
        t.y = avB0 + o1[3] + o2[3] + o3[3];
        __builtin_nontemporal_store(t, (f32x2*)(ov + c0));
        t.x = avA1 + o1[4] + o2[4] + o3[4];
        t.y = avB1 + o1[5] + o2[5] + o3[5];
        __builtin_nontemporal_store(t, (f32x2*)(ov + 128 + c0));
        t.x = avA2 + o1[6] + o2[6] + o3[6];
        t.y = avB2 + o1[7] + o2[7] + o3[7];
        __builtin_nontemporal_store(t, (f32x2*)(ov + 256 + c0));
    }
}

extern "C" void kernel_launch(void* const* d_in, const int* in_sizes, int n_in,
                              void* d_out, int out_size, void* d_ws, size_t ws_size,
                              hipStream_t stream) {
    const float* vectors    = (const float*)d_in[0];
    const float* scalars    = (const float*)d_in[1];
    const float* directions = (const float*)d_in[2];
    const int*   idx_i      = (const int*)d_in[3];
    const int*   idx_j      = (const int*)d_in[4];
    const float* W1         = (const float*)d_in[5];
    const float* b1         = (const float*)d_in[6];
    const float* W2         = (const float*)d_in[7];
    const float* b2         = (const float*)d_in[8];
    const float* Wr         = (const float*)d_in[9];
    const float* br         = (const float*)d_in[10];

    float* out_v = (float*)d_out;
    float* out_s = out_v + (size_t)A_NODES * 3 * FEAT;

    // workspace layout (16B-aligned chunks)
    char* ws = (char*)d_ws;
    ushort16* s_bf = (ushort16*)ws;  ws += (size_t)A_NODES * 384 * 2;      // 38.4 MB
    float* edata   = (float*)ws;     ws += (size_t)EDGES * 16 * 4;         // 32.0 MB
    uint32* wrpk   = (uint32*)ws;    ws += (size_t)10 * 384 * 4;           // 15.4 KB
    ushort16* w1pk = (ushort16*)ws;  ws += (size_t)16384 * 2;              // 32 KB
    ushort16* w2pk = (ushort16*)ws;  ws += (size_t)49152 * 2;              // 96 KB
    int* hist      = (int*)ws;       ws += (size_t)A_NODES * 4;
    int* offsets   = (int*)ws;       ws += (((size_t)(A_NODES + 1) * 4 + 15) & ~(size_t)15);
    int* cursor    = (int*)ws;       ws += (size_t)A_NODES * 4;
    ushort16* v_bf = (ushort16*)ws;  ws += (size_t)A_NODES * 384 * 2;      // 38.4 MB (optional)

    const int use_vbf = ((size_t)(ws - (char*)d_ws) <= ws_size) ? 1 : 0;

    hipMemsetAsync(hist, 0, (size_t)A_NODES * 4, stream);

    pack_kernel<<<271, 256, 0, stream>>>(W1, W2, Wr, w1pk, w2pk, wrpk);
    node_mlp_kernel<<<A_NODES / 16, 256, 0, stream>>>(scalars, w1pk, b1, w2pk, b2, s_bf);
    if (use_vbf)
        vec_cvt_kernel<<<(A_NODES * 384 / 2 + 255) / 256, 256, 0, stream>>>(vectors, (uint32*)v_bf);

    hist_kernel<<<(EDGES + 255) / 256, 256, 0, stream>>>(idx_j, hist);
    scan_kernel<<<1, 1024, 0, stream>>>(hist, offsets, cursor);
    edge_prep_kernel<<<(EDGES + 255) / 256, 256, 0, stream>>>(
        directions, idx_i, idx_j, cursor, edata);

    if (use_vbf)
        gather_kernel<1><<<A_NODES, 256, 0, stream>>>(
            s_bf, v_bf, vectors, wrpk, br, edata, offsets, out_v, out_s);
    else
        gather_kernel<0><<<A_NODES, 256, 0, stream>>>(
            s_bf, v_bf, vectors, wrpk, br, edata, offsets, out_v, out_s);
}

// Round 2
// 571.598 us; speedup vs baseline: 1.1332x; 1.0728x over previous
//
#include <hip/hip_runtime.h>
#include <math.h>

#define A_NODES 50000
#define FEAT 128
#define EDGES 500000
#define NRBF 20
#define CUTOFF_F 5.0f
#define PI_OVER_CUTOFF 0.6283185307179586f

typedef unsigned int uint32;
typedef unsigned short ushort16;
typedef short bf16x8 __attribute__((ext_vector_type(8)));
typedef float f32x4 __attribute__((ext_vector_type(4)));
typedef float f32x2 __attribute__((ext_vector_type(2)));

__device__ __forceinline__ ushort16 f2bf(float f) {
    union { float f; uint32 u; } v; v.f = f;
    uint32 r = (v.u + 0x7fffu + ((v.u >> 16) & 1u)) >> 16;   // RNE
    return (ushort16)r;
}
__device__ __forceinline__ uint32 packbf(float a, float b) {
    return (uint32)f2bf(a) | ((uint32)f2bf(b) << 16);
}
__device__ __forceinline__ float bf_lo(uint32 u) { return __uint_as_float(u << 16); }
__device__ __forceinline__ float bf_hi(uint32 u) { return __uint_as_float(u & 0xffff0000u); }

#if __has_builtin(__builtin_amdgcn_fdot2_f32_bf16)
typedef __bf16 bf16x2 __attribute__((ext_vector_type(2)));
__device__ __forceinline__ float dot2(uint32 a, uint32 b, float c) {
    return __builtin_amdgcn_fdot2_f32_bf16(
        __builtin_bit_cast(bf16x2, a), __builtin_bit_cast(bf16x2, b), c, false);
}
#else
__device__ __forceinline__ float dot2(uint32 a, uint32 b, float c) {
    return fmaf(bf_hi(a), bf_hi(b), fmaf(bf_lo(a), bf_lo(b), c));
}
#endif

// ---------------------------------------------------------------------------
// Weight packing: W1/W2 into MFMA B-fragment order (bf16), Wr into k-pair
// packed bf16x2 (gather layout).
// ---------------------------------------------------------------------------
__global__ __launch_bounds__(256) void pack_kernel(
    const float* __restrict__ W1, const float* __restrict__ W2,
    const float* __restrict__ Wr,
    ushort16* __restrict__ w1pk, ushort16* __restrict__ w2pk,
    uint32* __restrict__ wrpk)
{
    const int t = blockIdx.x * 256 + threadIdx.x;
    if (t < 16384) {
        const int jj = t & 7, l = (t >> 3) & 63, kk = (t >> 9) & 3, nt = t >> 11;
        const int col = (l & 15) + 16 * nt;
        const int k   = kk * 32 + (l >> 4) * 8 + jj;
        w1pk[t] = f2bf(W1[k * 128 + col]);
    } else if (t < 16384 + 49152) {
        const int u = t - 16384;
        const int jj = u & 7, l = (u >> 3) & 63, kk = (u >> 9) & 3, nt = u >> 11;
        const int col = (l & 15) + 16 * nt;
        const int k   = kk * 32 + (l >> 4) * 8 + jj;
        w2pk[u] = f2bf(W2[k * 384 + col]);
    } else if (t < 16384 + 49152 + 3840) {
        const int u = t - 16384 - 49152;
        const int m = u / 384, col = u % 384;
        wrpk[u] = packbf(Wr[(2 * m) * 384 + col], Wr[(2 * m + 1) * 384 + col]);
    }
}

// ---------------------------------------------------------------------------
// Kernel 1: node MLP via MFMA. 16 nodes/block, 4 waves.
// ---------------------------------------------------------------------------
__global__ __launch_bounds__(256) void node_mlp_kernel(
    const float* __restrict__ scalars,
    const ushort16* __restrict__ w1pk, const float* __restrict__ bias1,
    const ushort16* __restrict__ w2pk, const float* __restrict__ bias2,
    ushort16* __restrict__ s_bf)
{
    __shared__ ushort16 sc[16][136];
    __shared__ ushort16 hd[16][136];
    const int tx   = threadIdx.x;
    const int lane = tx & 63;
    const int wv   = tx >> 6;                 // 0..3
    const int base = blockIdx.x * 16;

    {
        const int row = tx >> 4;              // 0..15
        const int cs  = (tx & 15) * 8;        // 0,8,...,120
        const float* src = scalars + (size_t)(base + row) * FEAT + cs;
        const float4 f0 = *(const float4*)src;
        const float4 f1 = *(const float4*)(src + 4);
        bf16x8 tmp;
        tmp[0] = (short)f2bf(f0.x); tmp[1] = (short)f2bf(f0.y);
        tmp[2] = (short)f2bf(f0.z); tmp[3] = (short)f2bf(f0.w);
        tmp[4] = (short)f2bf(f1.x); tmp[5] = (short)f2bf(f1.y);
        tmp[6] = (short)f2bf(f1.z); tmp[7] = (short)f2bf(f1.w);
        *(bf16x8*)&sc[row][cs] = tmp;
    }
    __syncthreads();

    const int arow = lane & 15;
    const int kgrp = lane >> 4;               // 0..3

    // ---- layer 1 ----
    f32x4 acc0 = {0.f, 0.f, 0.f, 0.f};
    f32x4 acc1 = {0.f, 0.f, 0.f, 0.f};
    #pragma unroll
    for (int kk = 0; kk < 4; ++kk) {
        const bf16x8 a  = *(const bf16x8*)&sc[arow][kk * 32 + kgrp * 8];
        const bf16x8 b0 = *(const bf16x8*)(w1pk + (((size_t)(wv * 2 + 0) * 4 + kk) * 64 + lane) * 8);
        const bf16x8 b1 = *(const bf16x8*)(w1pk + (((size_t)(wv * 2 + 1) * 4 + kk) * 64 + lane) * 8);
        acc0 = __builtin_amdgcn_mfma_f32_16x16x32_bf16(a, b0, acc0, 0, 0, 0);
        acc1 = __builtin_amdgcn_mfma_f32_16x16x32_bf16(a, b1, acc1, 0, 0, 0);
    }
    {
        const int c0 = wv * 32 + (lane & 15);
        const int c1 = c0 + 16;
        const float bb0 = bias1[c0], bb1 = bias1[c1];
        #pragma unroll
        for (int r = 0; r < 4; ++r) {
            const int row = kgrp * 4 + r;
            float x0 = acc0[r] + bb0;
            float x1 = acc1[r] + bb1;
            x0 = x0 / (1.0f + __expf(-x0));
            x1 = x1 / (1.0f + __expf(-x1));
            hd[row][c0] = f2bf(x0);
            hd[row][c1] = f2bf(x1);
        }
    }
    __syncthreads();

    // ---- layer 2 ----
    f32x4 acc[6];
    #pragma unroll
    for (int n = 0; n < 6; ++n) acc[n] = (f32x4){0.f, 0.f, 0.f, 0.f};
    #pragma unroll
    for (int kk = 0; kk < 4; ++kk) {
        const bf16x8 a = *(const bf16x8*)&hd[arow][kk * 32 + kgrp * 8];
        #pragma unroll
        for (int n = 0; n < 6; ++n) {
            const bf16x8 b = *(const bf16x8*)(w2pk + (((size_t)(wv * 6 + n) * 4 + kk) * 64 + lane) * 8);
            acc[n] = __builtin_amdgcn_mfma_f32_16x16x32_bf16(a, b, acc[n], 0, 0, 0);
        }
    }
    #pragma unroll
    for (int n = 0; n < 6; ++n) {
        const int col = (wv * 6 + n) * 16 + (lane & 15);
        const float bb = bias2[col];
        #pragma unroll
        for (int r = 0; r < 4; ++r) {
            const int row = kgrp * 4 + r;
            s_bf[(size_t)(base + row) * 384 + col] = f2bf(acc[n][r] + bb);
        }
    }
}

// ---------------------------------------------------------------------------
// vectors fp32 -> bf16 (8 floats / thread)
// ---------------------------------------------------------------------------
__global__ __launch_bounds__(256) void vec_cvt_kernel(
    const float* __restrict__ vin, uint4* __restrict__ vbf)
{
    const size_t t = (size_t)blockIdx.x * 256 + threadIdx.x;   // 8-float chunk
    const size_t n8 = (size_t)A_NODES * 384 / 8;
    if (t < n8) {
        const float4 f0 = ((const float4*)vin)[2 * t];
        const float4 f1 = ((const float4*)vin)[2 * t + 1];
        uint4 o;
        o.x = packbf(f0.x, f0.y); o.y = packbf(f0.z, f0.w);
        o.z = packbf(f1.x, f1.y); o.w = packbf(f1.z, f1.w);
        vbf[t] = o;
    }
}

// ---------------------------------------------------------------------------
// CSR build
// ---------------------------------------------------------------------------
__global__ __launch_bounds__(256) void hist_kernel(
    const int* __restrict__ idx_j, int* __restrict__ hist)
{
    const int e = blockIdx.x * 256 + threadIdx.x;
    if (e < EDGES) atomicAdd(&hist[idx_j[e]], 1);
}

__global__ __launch_bounds__(1024) void scan_kernel(
    const int* __restrict__ hist, int* __restrict__ offsets,
    int* __restrict__ cursor)
{
    __shared__ int part[1024];
    const int t = threadIdx.x;
    const int CH = (A_NODES + 1023) / 1024;

    int sum = 0;
    for (int k = 0; k < CH; ++k) {
        const int idx = t * CH + k;
        if (idx < A_NODES) sum += hist[idx];
    }
    part[t] = sum;
    __syncthreads();
    for (int off = 1; off < 1024; off <<= 1) {
        const int v = (t >= off) ? part[t - off] : 0;
        __syncthreads();
        part[t] += v;
        __syncthreads();
    }
    int run = part[t] - sum;
    for (int k = 0; k < CH; ++k) {
        const int idx = t * CH + k;
        if (idx < A_NODES) {
            offsets[idx] = run;
            cursor[idx]  = run;
            run += hist[idx];
        }
    }
    if (t == 0) offsets[A_NODES] = EDGES;
}

// ---------------------------------------------------------------------------
// Edge prep FUSED with scatter: writes edata[pos] directly.
// 16 dwords per position p:
//   [0..9]  rbf*invn*fc packed bf16x2 (k pairs)
//   [10..12] unit dir, [13] fc, [14] idx_i bits, [15] pad
// ---------------------------------------------------------------------------
__global__ __launch_bounds__(256) void edge_prep_kernel(
    const float* __restrict__ directions,
    const int* __restrict__ idx_i, const int* __restrict__ idx_j,
    int* __restrict__ cursor,
    float* __restrict__ edata)
{
    const int e = blockIdx.x * 256 + threadIdx.x;
    if (e >= EDGES) return;
    const int j   = idx_j[e];
    const int pos = atomicAdd(&cursor[j], 1);
    const int i   = idx_i[e];
    const float d0 = directions[(size_t)e * 3 + 0];
    const float d1 = directions[(size_t)e * 3 + 1];
    const float d2 = directions[(size_t)e * 3 + 2];
    const float nr   = sqrtf(d0 * d0 + d1 * d1 + d2 * d2);
    const float invn = 1.0f / nr;
    const float x = PI_OVER_CUTOFF * nr;
    float sx, cx;
    sincosf(x, &sx, &cx);
    const float fc = (nr < CUTOFF_F) ? 0.5f * (cx + 1.0f) : 0.0f;
    const float scale = invn * fc;
    const float twoc = 2.0f * cx;

    float out16[16];
    float s_odd = sx;      // sin((2m+1)x)
    float s_prev = 0.0f;   // sin(2m x)
    #pragma unroll
    for (int m = 0; m < 10; ++m) {
        const float s_even = twoc * s_odd - s_prev;       // sin((2m+2)x)
        out16[m] = __uint_as_float(packbf(s_odd * scale, s_even * scale));
        const float s_next = twoc * s_even - s_odd;       // sin((2m+3)x)
        s_prev = s_even;
        s_odd  = s_next;
    }
    out16[10] = d0 * invn;
    out16[11] = d1 * invn;
    out16[12] = d2 * invn;
    out16[13] = fc;
    out16[14] = __int_as_float(i);
    out16[15] = 0.0f;

    float4* dst = (float4*)(edata + (size_t)pos * 16);
    dst[0] = make_float4(out16[0],  out16[1],  out16[2],  out16[3]);
    dst[1] = make_float4(out16[4],  out16[5],  out16[6],  out16[7]);
    dst[2] = make_float4(out16[8],  out16[9],  out16[10], out16[11]);
    dst[3] = make_float4(out16[12], out16[13], out16[14], out16[15]);
}

// ---------------------------------------------------------------------------
// Gather: 1 wave per node, 4 nodes per block. No LDS, no syncthreads.
// Wr columns live in 30 NAMED uint2 registers (no arrays -> no scratch,
// no per-edge reload). Lane owns cols 2*lane, 2*lane+1.
// ---------------------------------------------------------------------------
template <int VBF>
__global__ __launch_bounds__(256, 4) void gather_kernel(
    const ushort16* __restrict__ s_bf,
    const ushort16* __restrict__ v_bf,
    const float* __restrict__ vectors_f32,
    const uint32* __restrict__ wrpk, const float* __restrict__ br,
    const float* __restrict__ edata,
    const int* __restrict__ offsets,
    float* __restrict__ out_v, float* __restrict__ out_s)
{
    const int lane = threadIdx.x & 63;
    const int wv   = threadIdx.x >> 6;        // 0..3
    const int j    = blockIdx.x * 4 + wv;
    const int c0   = lane * 2;

    // 30 named weight pairs: w<s><m> holds cols (c0, c0+1) of segment s, k-pair m
#define LDW(s, m) (*(const uint2*)(wrpk + (m) * 384 + (s) * 128 + c0))
    const uint2 w00 = LDW(0,0), w01 = LDW(0,1), w02 = LDW(0,2), w03 = LDW(0,3), w04 = LDW(0,4);
    const uint2 w05 = LDW(0,5), w06 = LDW(0,6), w07 = LDW(0,7), w08 = LDW(0,8), w09 = LDW(0,9);
    const uint2 w10 = LDW(1,0), w11 = LDW(1,1), w12 = LDW(1,2), w13 = LDW(1,3), w14 = LDW(1,4);
    const uint2 w15 = LDW(1,5), w16 = LDW(1,6), w17 = LDW(1,7), w18 = LDW(1,8), w19 = LDW(1,9);
    const uint2 w20 = LDW(2,0), w21 = LDW(2,1), w22 = LDW(2,2), w23 = LDW(2,3), w24 = LDW(2,4);
    const uint2 w25 = LDW(2,5), w26 = LDW(2,6), w27 = LDW(2,7), w28 = LDW(2,8), w29 = LDW(2,9);
#undef LDW
    const float2 brv0 = *(const float2*)(br + c0);
    const float2 brv1 = *(const float2*)(br + 128 + c0);
    const float2 brv2 = *(const float2*)(br + 256 + c0);

    const int beg = offsets[j];
    const int end = offsets[j + 1];

    float accsA = 0.f, accsB = 0.f;
    float avA0 = 0.f, avA1 = 0.f, avA2 = 0.f;
    float avB0 = 0.f, avB1 = 0.f, avB2 = 0.f;

    int p = beg;
    float4 cA, cB, cC, cD;
    if (p < end) {
        const float4* s0p = (const float4*)(edata + (size_t)p * 16);
        cA = s0p[0]; cB = s0p[1]; cC = s0p[2]; cD = s0p[3];
    }

    while (p < end) {
        const int pn = p + 1;
        const int i  = __float_as_int(cD.z);     // ed[14]

        // gathers for current edge (latency hidden under dot2 chain)
        const ushort16* srow = s_bf + (size_t)i * 384;
        const uint32 s0 = *(const uint32*)(srow + c0);
        const uint32 s1 = *(const uint32*)(srow + 128 + c0);
        const uint32 s2 = *(const uint32*)(srow + 256 + c0);

        float vA0, vB0, vA1, vB1, vA2, vB2;
        if (VBF) {
            const ushort16* vrow = v_bf + (size_t)i * 384;
            const uint32 v0 = *(const uint32*)(vrow + c0);
            const uint32 v1 = *(const uint32*)(vrow + 128 + c0);
            const uint32 v2 = *(const uint32*)(vrow + 256 + c0);
            vA0 = bf_lo(v0); vB0 = bf_hi(v0);
            vA1 = bf_lo(v1); vB1 = bf_hi(v1);
            vA2 = bf_lo(v2); vB2 = bf_hi(v2);
        } else {
            const float* vrow = vectors_f32 + (size_t)i * 384;
            vA0 = vrow[c0];       vB0 = vrow[c0 + 1];
            vA1 = vrow[128 + c0]; vB1 = vrow[129 + c0];
            vA2 = vrow[256 + c0]; vB2 = vrow[257 + c0];
        }

        // prefetch next edata row (clamped; uniform)
        const size_t pf = (size_t)(pn < end ? pn : p) * 16;
        const float4* sn = (const float4*)(edata + pf);
        const float4 nA = sn[0], nB = sn[1], nC = sn[2], nD = sn[3];

        const uint32 b0 = __float_as_uint(cA.x), b1 = __float_as_uint(cA.y);
        const uint32 b2 = __float_as_uint(cA.z), b3 = __float_as_uint(cA.w);
        const uint32 b4 = __float_as_uint(cB.x), b5 = __float_as_uint(cB.y);
        const uint32 b6 = __float_as_uint(cB.z), b7 = __float_as_uint(cB.w);
        const uint32 b8 = __float_as_uint(cC.x), b9 = __float_as_uint(cC.y);
        const float u0 = cC.z, u1 = cC.w, u2 = cD.x, fcv = cD.y;

        float rA0 = fcv * brv0.x, rB0 = fcv * brv0.y;
        float rA1 = fcv * brv1.x, rB1 = fcv * brv1.y;
        float rA2 = fcv * brv2.x, rB2 = fcv * brv2.y;

#define DOTS(bb, wa, wb, wc) \
        rA0 = dot2(bb, wa.x, rA0); rB0 = dot2(bb, wa.y, rB0); \
        rA1 = dot2(bb, wb.x, rA1); rB1 = dot2(bb, wb.y, rB1); \
        rA2 = dot2(bb, wc.x, rA2); rB2 = dot2(bb, wc.y, rB2);
        DOTS(b0, w00, w10, w20)
        DOTS(b1, w01, w11, w21)
        DOTS(b2, w02, w12, w22)
        DOTS(b3, w03, w13, w23)
        DOTS(b4, w04, w14, w24)
        DOTS(b5, w05, w15, w25)
        DOTS(b6, w06, w16, w26)
        DOTS(b7, w07, w17, w27)
        DOTS(b8, w08, w18, w28)
        DOTS(b9, w09, w19, w29)
#undef DOTS

        const float sA0 = bf_lo(s0), sB0 = bf_hi(s0);
        const float sA1 = bf_lo(s1), sB1 = bf_hi(s1);
        const float sA2 = bf_lo(s2), sB2 = bf_hi(s2);

        accsA = fmaf(sA0, rA0, accsA);
        accsB = fmaf(sB0, rB0, accsB);
        const float gA1 = sA1 * rA1, gA2 = sA2 * rA2;
        const float gB1 = sB1 * rB1, gB2 = sB2 * rB2;

        avA0 = fmaf(vA0, gA1, fmaf(gA2, u0, avA0));
        avB0 = fmaf(vB0, gB1, fmaf(gB2, u0, avB0));
        avA1 = fmaf(vA1, gA1, fmaf(gA2, u1, avA1));
        avB1 = fmaf(vB1, gB1, fmaf(gB2, u1, avB1));
        avA2 = fmaf(vA2, gA1, fmaf(gA2, u2, avA2));
        avB2 = fmaf(vB2, gB1, fmaf(gB2, u2, avB2));

        cA = nA; cB = nB; cC = nC; cD = nD;
        p = pn;
    }

    // direct store (covers zero-degree nodes with zeros)
    f32x2 t;
    t.x = accsA; t.y = accsB;
    __builtin_nontemporal_store(t, (f32x2*)(out_s + (size_t)j * 128 + c0));
    float* ov = out_v + (size_t)j * 384;
    t.x = avA0; t.y = avB0;
    __builtin_nontemporal_store(t, (f32x2*)(ov + c0));
    t.x = avA1; t.y = avB1;
    __builtin_nontemporal_store(t, (f32x2*)(ov + 128 + c0));
    t.x = avA2; t.y = avB2;
    __builtin_nontemporal_store(t, (f32x2*)(ov + 256 + c0));
}

extern "C" void kernel_launch(void* const* d_in, const int* in_sizes, int n_in,
                              void* d_out, int out_size, void* d_ws, size_t ws_size,
                              hipStream_t stream) {
    const float* vectors    = (const float*)d_in[0];
    const float* scalars    = (const float*)d_in[1];
    const float* directions = (const float*)d_in[2];
    const int*   idx_i      = (const int*)d_in[3];
    const int*   idx_j      = (const int*)d_in[4];
    const float* W1         = (const float*)d_in[5];
    const float* b1         = (const float*)d_in[6];
    const float* W2         = (const float*)d_in[7];
    const float* b2         = (const float*)d_in[8];
    const float* Wr         = (const float*)d_in[9];
    const float* br         = (const float*)d_in[10];

    float* out_v = (float*)d_out;
    float* out_s = out_v + (size_t)A_NODES * 3 * FEAT;

    // workspace layout (16B-aligned chunks)
    char* ws = (char*)d_ws;
    ushort16* s_bf = (ushort16*)ws;  ws += (size_t)A_NODES * 384 * 2;      // 38.4 MB
    float* edata   = (float*)ws;     ws += (size_t)EDGES * 16 * 4;         // 32.0 MB
    uint32* wrpk   = (uint32*)ws;    ws += (size_t)10 * 384 * 4;           // 15.4 KB
    ushort16* w1pk = (ushort16*)ws;  ws += (size_t)16384 * 2;              // 32 KB
    ushort16* w2pk = (ushort16*)ws;  ws += (size_t)49152 * 2;              // 96 KB
    int* hist      = (int*)ws;       ws += (size_t)A_NODES * 4;
    int* offsets   = (int*)ws;       ws += (((size_t)(A_NODES + 1) * 4 + 15) & ~(size_t)15);
    int* cursor    = (int*)ws;       ws += (size_t)A_NODES * 4;
    ushort16* v_bf = (ushort16*)ws;  ws += (size_t)A_NODES * 384 * 2;      // 38.4 MB (optional)

    const int use_vbf = ((size_t)(ws - (char*)d_ws) <= ws_size) ? 1 : 0;

    hipMemsetAsync(hist, 0, (size_t)A_NODES * 4, stream);

    pack_kernel<<<271, 256, 0, stream>>>(W1, W2, Wr, w1pk, w2pk, wrpk);
    node_mlp_kernel<<<A_NODES / 16, 256, 0, stream>>>(scalars, w1pk, b1, w2pk, b2, s_bf);
    if (use_vbf)
        vec_cvt_kernel<<<(int)(((size_t)A_NODES * 384 / 8 + 255) / 256), 256, 0, stream>>>(
            vectors, (uint4*)v_bf);

    hist_kernel<<<(EDGES + 255) / 256, 256, 0, stream>>>(idx_j, hist);
    scan_kernel<<<1, 1024, 0, stream>>>(hist, offsets, cursor);
    edge_prep_kernel<<<(EDGES + 255) / 256, 256, 0, stream>>>(
        directions, idx_i, idx_j, cursor, edata);

    if (use_vbf)
        gather_kernel<1><<<A_NODES / 4, 256, 0, stream>>>(
            s_bf, v_bf, vectors, wrpk, br, edata, offsets, out_v, out_s);
    else
        gather_kernel<0><<<A_NODES / 4, 256, 0, stream>>>(
            s_bf, v_bf, vectors, wrpk, br, edata, offsets, out_v, out_s);
}